// Round 3
// baseline (13400.861 us; speedup 1.0000x reference)
//
#include <hip/hip_runtime.h>
#include <hip/hip_bf16.h>

#define NN 8192
#define DD 64
#define NITER 100

typedef unsigned short u16;
typedef unsigned int u32;

static constexpr float INV_EPS = 10.0f;          // 1/epsilon
static constexpr float MARG    = 1.0f / 8192.0f; // a_i = b_j = u0_i = 1/n

// Unpack 8 bf16 (packed in uint4) -> 8 f32 (exact: bf16 is truncated f32)
__device__ __forceinline__ void unpack8(const uint4 q, float f[8]) {
  f[0] = __uint_as_float(q.x << 16); f[1] = __uint_as_float(q.x & 0xffff0000u);
  f[2] = __uint_as_float(q.y << 16); f[3] = __uint_as_float(q.y & 0xffff0000u);
  f[4] = __uint_as_float(q.z << 16); f[5] = __uint_as_float(q.z & 0xffff0000u);
  f[6] = __uint_as_float(q.w << 16); f[7] = __uint_as_float(q.w & 0xffff0000u);
}

// Pack two f32 -> u32 of 2 bf16 (RNE), low half = first element
__device__ __forceinline__ u32 pkbf2(float a, float b) {
  __hip_bfloat16 ha = __float2bfloat16(a), hb = __float2bfloat16(b);
  return (u32)*reinterpret_cast<u16*>(&ha) | ((u32)*reinterpret_cast<u16*>(&hb) << 16);
}

// ---------------------------------------------------------------------------
// Kernel 1: row norms of x and y. 16384 threads, one row each.
__global__ __launch_bounds__(256) void norms_k(const float* __restrict__ x,
                                               const float* __restrict__ y,
                                               float* __restrict__ xx,
                                               float* __restrict__ yy) {
  int idx = blockIdx.x * 256 + threadIdx.x;       // 0..16383
  const float* src = (idx < NN) ? (x + (size_t)idx * DD)
                                : (y + (size_t)(idx - NN) * DD);
  const float4* p = (const float4*)src;
  float s = 0.f;
#pragma unroll
  for (int i = 0; i < 16; i++) {
    float4 v = p[i];
    s += v.x * v.x + v.y * v.y + v.z * v.z + v.w * v.w;
  }
  if (idx < NN) xx[idx] = s; else yy[idx - NN] = s;
}

// ---------------------------------------------------------------------------
// Kernel 2: build K (bf16) as LDS-tiled f32 GEMM. 64x128 tile, micro 4x8.
__global__ __launch_bounds__(256) void build_k(const float* __restrict__ x,
                                               const float* __restrict__ y,
                                               const float* __restrict__ xx,
                                               const float* __restrict__ yy,
                                               u16* __restrict__ K) {
  __shared__ float xs[64][64];    // [k][row]  16 KB
  __shared__ float ys[64][128];   // [k][col]  32 KB

  int t  = threadIdx.x;
  int ib = blockIdx.x & 127;      // row block 0..127
  int jb = blockIdx.x >> 7;       // col block 0..63
  int i0 = ib * 64;
  int j0 = jb * 128;

  {
    int row = t >> 2, kc = (t & 3) * 16;
    const float4* src = (const float4*)(x + (size_t)(i0 + row) * DD + kc);
#pragma unroll
    for (int c = 0; c < 4; c++) {
      float4 v = src[c];
      xs[kc + c * 4 + 0][row] = v.x;
      xs[kc + c * 4 + 1][row] = v.y;
      xs[kc + c * 4 + 2][row] = v.z;
      xs[kc + c * 4 + 3][row] = v.w;
    }
  }
  {
    int col = t >> 1, kc = (t & 1) * 32;
    const float4* src = (const float4*)(y + (size_t)(j0 + col) * DD + kc);
#pragma unroll
    for (int c = 0; c < 8; c++) {
      float4 v = src[c];
      ys[kc + c * 4 + 0][col] = v.x;
      ys[kc + c * 4 + 1][col] = v.y;
      ys[kc + c * 4 + 2][col] = v.z;
      ys[kc + c * 4 + 3][col] = v.w;
    }
  }
  __syncthreads();

  int tr = (t >> 4) * 4;          // row offset within tile
  int tc = (t & 15) * 8;          // col offset within tile

  float acc[4][8];
#pragma unroll
  for (int r = 0; r < 4; r++)
#pragma unroll
    for (int c = 0; c < 8; c++) acc[r][c] = 0.f;

#pragma unroll 4
  for (int k = 0; k < DD; k++) {
    float4 xa = *(const float4*)&xs[k][tr];
    float4 y0 = *(const float4*)&ys[k][tc];
    float4 y1 = *(const float4*)&ys[k][tc + 4];
    float xv[4] = {xa.x, xa.y, xa.z, xa.w};
    float yv[8] = {y0.x, y0.y, y0.z, y0.w, y1.x, y1.y, y1.z, y1.w};
#pragma unroll
    for (int r = 0; r < 4; r++)
#pragma unroll
      for (int c = 0; c < 8; c++) acc[r][c] += xv[r] * yv[c];
  }

  float xn[4], yn[8];
#pragma unroll
  for (int r = 0; r < 4; r++) xn[r] = xx[i0 + tr + r];
#pragma unroll
  for (int c = 0; c < 8; c++) yn[c] = yy[j0 + tc + c];

#pragma unroll
  for (int r = 0; r < 4; r++) {
    u16 outp[8];
#pragma unroll
    for (int c = 0; c < 8; c++) {
      float sq = xn[r] + yn[c] - 2.f * acc[r][c];
      sq = fmaxf(sq, 1e-12f);
      float kv = __expf(-sqrtf(sq) * INV_EPS);
      __hip_bfloat16 h = __float2bfloat16(kv);
      outp[c] = *reinterpret_cast<u16*>(&h);
    }
    *(uint4*)(K + (size_t)(i0 + tr + r) * NN + j0 + tc) = *(uint4*)outp;
  }
}

// ---------------------------------------------------------------------------
// Kernel 3: initial column partials (u0 = 1/n), P bf16.
__global__ __launch_bounds__(256) void col0_k(const u16* __restrict__ K,
                                              u16* __restrict__ P) {
  int t = threadIdx.x;
  int b = blockIdx.x;
  int i0 = b * 16;
  float acc[4][8];
#pragma unroll
  for (int c = 0; c < 4; c++)
#pragma unroll
    for (int e = 0; e < 8; e++) acc[c][e] = 0.f;

  for (int r = 0; r < 16; r++) {
#pragma unroll
    for (int c = 0; c < 4; c++) {
      uint4 q = *(const uint4*)(K + (size_t)(i0 + r) * NN + c * 2048 + t * 8);
      float f[8];
      unpack8(q, f);
#pragma unroll
      for (int e = 0; e < 8; e++) acc[c][e] += f[e];
    }
  }
#pragma unroll
  for (int c = 0; c < 4; c++) {
    uint4 w;
    w.x = pkbf2(acc[c][0] * MARG, acc[c][1] * MARG);
    w.y = pkbf2(acc[c][2] * MARG, acc[c][3] * MARG);
    w.z = pkbf2(acc[c][4] * MARG, acc[c][5] * MARG);
    w.w = pkbf2(acc[c][6] * MARG, acc[c][7] * MARG);
    *(uint4*)(P + (size_t)b * NN + c * 2048 + t * 8) = w;
  }
}

// ---------------------------------------------------------------------------
// Kernel 4: reduce bf16 partials -> v[j] = b_j / sum_k P[k][j].
// 256 blocks x 32 cols (16 col-pairs). Thread (jjp=t&15, kk=t>>4) sums 32
// partial rows for its col-pair (one u32 = 2 bf16 per load).
__global__ __launch_bounds__(256) void red_k(const u16* __restrict__ P,
                                             float* __restrict__ v) {
  int t = threadIdx.x;
  int j0 = blockIdx.x * 32;
  int jjp = t & 15;               // col-pair 0..15
  int kk  = t >> 4;               // 0..15, 32 partial rows each
  float s0 = 0.f, s1 = 0.f;
#pragma unroll 8
  for (int k = kk * 32; k < kk * 32 + 32; k++) {
    u32 w = *(const u32*)(P + (size_t)k * NN + j0 + jjp * 2);
    s0 += __uint_as_float(w << 16);
    s1 += __uint_as_float(w & 0xffff0000u);
  }
  __shared__ float red[256][2];
  red[t][0] = s0;
  red[t][1] = s1;
  __syncthreads();
  if (t < 16) {
    float t0 = 0.f, t1 = 0.f;
#pragma unroll
    for (int k = 0; k < 16; k++) {
      t0 += red[k * 16 + t][0];
      t1 += red[k * 16 + t][1];
    }
    v[j0 + t * 2]     = MARG / t0;
    v[j0 + t * 2 + 1] = MARG / t1;
  }
}

// ---------------------------------------------------------------------------
// Kernel 5 (hot loop): fused row-dot + column-partial, pipelined.
// Block = 16 rows, processed as 4 groups of 4 rows. Per group: one barrier
// (wave-shfl reduce -> per-wave LDS partials, double-buffered; every thread
// redundantly computes u). Next group's K loads prefetched during compute.
__global__ __launch_bounds__(256, 2) void fused_k(const u16* __restrict__ K,
                                                  const float* __restrict__ vin,
                                                  float* __restrict__ uout,
                                                  u16* __restrict__ P) {
  int t = threadIdx.x;
  int b = blockIdx.x;
  int i0 = b * 16;
  int wave = t >> 6;

  // v values for this thread's 32 columns
  float vv[4][8];
#pragma unroll
  for (int c = 0; c < 4; c++) {
    const float* vp = vin + c * 2048 + t * 8;
    float4 a = *(const float4*)vp;
    float4 bq = *(const float4*)(vp + 4);
    vv[c][0] = a.x;  vv[c][1] = a.y;  vv[c][2] = a.z;  vv[c][3] = a.w;
    vv[c][4] = bq.x; vv[c][5] = bq.y; vv[c][6] = bq.z; vv[c][7] = bq.w;
  }

  float acc[4][8];
#pragma unroll
  for (int c = 0; c < 4; c++)
#pragma unroll
    for (int e = 0; e < 8; e++) acc[c][e] = 0.f;

  __shared__ float wsum[2][4][4];   // [buf][wave][row]

  uint4 q[4][4];                    // [row][c] current group
#pragma unroll
  for (int r = 0; r < 4; r++)
#pragma unroll
    for (int c = 0; c < 4; c++)
      q[r][c] = *(const uint4*)(K + (size_t)(i0 + r) * NN + c * 2048 + t * 8);

#pragma unroll
  for (int rg = 0; rg < 4; rg++) {
    int ibase = i0 + rg * 4;
    uint4 qn[4][4];
    if (rg < 3) {
#pragma unroll
      for (int r = 0; r < 4; r++)
#pragma unroll
        for (int c = 0; c < 4; c++)
          qn[r][c] = *(const uint4*)(K + (size_t)(ibase + 4 + r) * NN + c * 2048 + t * 8);
    }

    // row dots for 4 rows (32 cols per thread)
    float s[4];
#pragma unroll
    for (int r = 0; r < 4; r++) {
      float sr = 0.f;
#pragma unroll
      for (int c = 0; c < 4; c++) {
        float f[8];
        unpack8(q[r][c], f);
#pragma unroll
        for (int e = 0; e < 8; e++) sr += f[e] * vv[c][e];
      }
      s[r] = sr;
    }
    // wave-level reduce
#pragma unroll
    for (int r = 0; r < 4; r++) {
#pragma unroll
      for (int o = 32; o > 0; o >>= 1) s[r] += __shfl_xor(s[r], o);
    }
    if ((t & 63) == 0) {
#pragma unroll
      for (int r = 0; r < 4; r++) wsum[rg & 1][wave][r] = s[r];
    }
    __syncthreads();

    float uu[4];
#pragma unroll
    for (int r = 0; r < 4; r++) {
      float tot = wsum[rg & 1][0][r] + wsum[rg & 1][1][r]
                + wsum[rg & 1][2][r] + wsum[rg & 1][3][r];
      uu[r] = MARG / tot;
    }
    if (t < 4) uout[ibase + t] = uu[t];

    // accumulate column partials
#pragma unroll
    for (int r = 0; r < 4; r++) {
#pragma unroll
      for (int c = 0; c < 4; c++) {
        float f[8];
        unpack8(q[r][c], f);
#pragma unroll
        for (int e = 0; e < 8; e++) acc[c][e] += f[e] * uu[r];
      }
    }

    if (rg < 3) {
#pragma unroll
      for (int r = 0; r < 4; r++)
#pragma unroll
        for (int c = 0; c < 4; c++)
          q[r][c] = qn[r][c];
    }
  }

#pragma unroll
  for (int c = 0; c < 4; c++) {
    uint4 w;
    w.x = pkbf2(acc[c][0], acc[c][1]);
    w.y = pkbf2(acc[c][2], acc[c][3]);
    w.z = pkbf2(acc[c][4], acc[c][5]);
    w.w = pkbf2(acc[c][6], acc[c][7]);
    *(uint4*)(P + (size_t)b * NN + c * 2048 + t * 8) = w;
  }
}

// ---------------------------------------------------------------------------
// Kernel 6: pi[i][j] = u_i * K[i][j] * v_j. 2048 blocks x 4 rows for latency
// hiding (write-BW bound).
__global__ __launch_bounds__(256) void pi_k(const u16* __restrict__ K,
                                            const float* __restrict__ u,
                                            const float* __restrict__ v,
                                            float* __restrict__ out) {
  int t = threadIdx.x;
  int b = blockIdx.x;
  int i0 = b * 4;

  float vv[4][8];
#pragma unroll
  for (int c = 0; c < 4; c++) {
    const float* vp = v + c * 2048 + t * 8;
    float4 a = *(const float4*)vp;
    float4 bq = *(const float4*)(vp + 4);
    vv[c][0] = a.x;  vv[c][1] = a.y;  vv[c][2] = a.z;  vv[c][3] = a.w;
    vv[c][4] = bq.x; vv[c][5] = bq.y; vv[c][6] = bq.z; vv[c][7] = bq.w;
  }

#pragma unroll
  for (int r = 0; r < 4; r++) {
    int i = i0 + r;
    float uv = u[i];
#pragma unroll
    for (int c = 0; c < 4; c++) {
      uint4 q = *(const uint4*)(K + (size_t)i * NN + c * 2048 + t * 8);
      float f[8];
      unpack8(q, f);
      float4 lo = {uv * f[0] * vv[c][0], uv * f[1] * vv[c][1],
                   uv * f[2] * vv[c][2], uv * f[3] * vv[c][3]};
      float4 hi = {uv * f[4] * vv[c][4], uv * f[5] * vv[c][5],
                   uv * f[6] * vv[c][6], uv * f[7] * vv[c][7]};
      float* dst = out + (size_t)i * NN + c * 2048 + t * 8;
      *(float4*)dst = lo;
      *(float4*)(dst + 4) = hi;
    }
  }
}

// ---------------------------------------------------------------------------
extern "C" void kernel_launch(void* const* d_in, const int* in_sizes, int n_in,
                              void* d_out, int out_size, void* d_ws, size_t ws_size,
                              hipStream_t stream) {
  const float* x = (const float*)d_in[0];
  const float* y = (const float*)d_in[1];
  float* out = (float*)d_out;

  char* ws = (char*)d_ws;
  u16*  K  = (u16*)ws;                                     // 128 MiB
  u16*  P  = (u16*)(ws + (size_t)NN * NN * 2);             // 8 MiB (512 x 8192 bf16)
  float* xx = (float*)(ws + (size_t)NN * NN * 2 + (size_t)512 * NN * 2);
  float* yy = xx + NN;
  float* u  = yy + NN;
  float* v  = u + NN;

  norms_k<<<(2 * NN) / 256, 256, 0, stream>>>(x, y, xx, yy);
  build_k<<<128 * 64, 256, 0, stream>>>(x, y, xx, yy, K);
  col0_k<<<NN / 16, 256, 0, stream>>>(K, P);               // P = partials of K^T u0

  for (int it = 0; it < NITER; it++) {
    red_k<<<NN / 32, 256, 0, stream>>>(P, v);              // v = b / (K^T u)
    fused_k<<<NN / 16, 256, 0, stream>>>(K, v, u, P);      // u = a/(Kv); P = partials K^T u
  }
  red_k<<<NN / 32, 256, 0, stream>>>(P, v);                // final v
  pi_k<<<NN / 4, 256, 0, stream>>>(K, u, v, out);          // pi = u * K * v
}

// Round 4
// 2992.428 us; speedup vs baseline: 4.4783x; 4.4783x over previous
//
#include <hip/hip_runtime.h>
#include <hip/hip_bf16.h>

#define NN 8192
#define DD 64
#define NITER 100

typedef unsigned short u16;
typedef unsigned int u32;

static constexpr float INV_EPS = 10.0f;          // 1/epsilon
static constexpr float MARG    = 1.0f / 8192.0f; // a_i = b_j = u0_i = 1/n

// Unpack 8 bf16 (packed in uint4) -> 8 f32 (exact: bf16 is truncated f32)
__device__ __forceinline__ void unpack8(const uint4 q, float f[8]) {
  f[0] = __uint_as_float(q.x << 16); f[1] = __uint_as_float(q.x & 0xffff0000u);
  f[2] = __uint_as_float(q.y << 16); f[3] = __uint_as_float(q.y & 0xffff0000u);
  f[4] = __uint_as_float(q.z << 16); f[5] = __uint_as_float(q.z & 0xffff0000u);
  f[6] = __uint_as_float(q.w << 16); f[7] = __uint_as_float(q.w & 0xffff0000u);
}

// Pack two f32 -> u32 of 2 bf16 (RNE), low half = first element
__device__ __forceinline__ u32 pkbf2(float a, float b) {
  __hip_bfloat16 ha = __float2bfloat16(a), hb = __float2bfloat16(b);
  return (u32)*reinterpret_cast<u16*>(&ha) | ((u32)*reinterpret_cast<u16*>(&hb) << 16);
}

// ---------------------------------------------------------------------------
// Kernel 1: row norms of x and y. 16384 threads, one row each.
__global__ __launch_bounds__(256) void norms_k(const float* __restrict__ x,
                                               const float* __restrict__ y,
                                               float* __restrict__ xx,
                                               float* __restrict__ yy) {
  int idx = blockIdx.x * 256 + threadIdx.x;       // 0..16383
  const float* src = (idx < NN) ? (x + (size_t)idx * DD)
                                : (y + (size_t)(idx - NN) * DD);
  const float4* p = (const float4*)src;
  float s = 0.f;
#pragma unroll
  for (int i = 0; i < 16; i++) {
    float4 v = p[i];
    s += v.x * v.x + v.y * v.y + v.z * v.z + v.w * v.w;
  }
  if (idx < NN) xx[idx] = s; else yy[idx - NN] = s;
}

// ---------------------------------------------------------------------------
// Kernel 2: build K (bf16) as LDS-tiled f32 GEMM. 64x128 tile, micro 4x8.
__global__ __launch_bounds__(256) void build_k(const float* __restrict__ x,
                                               const float* __restrict__ y,
                                               const float* __restrict__ xx,
                                               const float* __restrict__ yy,
                                               u16* __restrict__ K) {
  __shared__ float xs[64][64];    // [k][row]  16 KB
  __shared__ float ys[64][128];   // [k][col]  32 KB

  int t  = threadIdx.x;
  int ib = blockIdx.x & 127;      // row block 0..127
  int jb = blockIdx.x >> 7;       // col block 0..63
  int i0 = ib * 64;
  int j0 = jb * 128;

  {
    int row = t >> 2, kc = (t & 3) * 16;
    const float4* src = (const float4*)(x + (size_t)(i0 + row) * DD + kc);
#pragma unroll
    for (int c = 0; c < 4; c++) {
      float4 v = src[c];
      xs[kc + c * 4 + 0][row] = v.x;
      xs[kc + c * 4 + 1][row] = v.y;
      xs[kc + c * 4 + 2][row] = v.z;
      xs[kc + c * 4 + 3][row] = v.w;
    }
  }
  {
    int col = t >> 1, kc = (t & 1) * 32;
    const float4* src = (const float4*)(y + (size_t)(j0 + col) * DD + kc);
#pragma unroll
    for (int c = 0; c < 8; c++) {
      float4 v = src[c];
      ys[kc + c * 4 + 0][col] = v.x;
      ys[kc + c * 4 + 1][col] = v.y;
      ys[kc + c * 4 + 2][col] = v.z;
      ys[kc + c * 4 + 3][col] = v.w;
    }
  }
  __syncthreads();

  int tr = (t >> 4) * 4;          // row offset within tile
  int tc = (t & 15) * 8;          // col offset within tile

  float acc[4][8];
#pragma unroll
  for (int r = 0; r < 4; r++)
#pragma unroll
    for (int c = 0; c < 8; c++) acc[r][c] = 0.f;

#pragma unroll 4
  for (int k = 0; k < DD; k++) {
    float4 xa = *(const float4*)&xs[k][tr];
    float4 y0 = *(const float4*)&ys[k][tc];
    float4 y1 = *(const float4*)&ys[k][tc + 4];
    float xv[4] = {xa.x, xa.y, xa.z, xa.w};
    float yv[8] = {y0.x, y0.y, y0.z, y0.w, y1.x, y1.y, y1.z, y1.w};
#pragma unroll
    for (int r = 0; r < 4; r++)
#pragma unroll
      for (int c = 0; c < 8; c++) acc[r][c] += xv[r] * yv[c];
  }

  float xn[4], yn[8];
#pragma unroll
  for (int r = 0; r < 4; r++) xn[r] = xx[i0 + tr + r];
#pragma unroll
  for (int c = 0; c < 8; c++) yn[c] = yy[j0 + tc + c];

#pragma unroll
  for (int r = 0; r < 4; r++) {
    u16 outp[8];
#pragma unroll
    for (int c = 0; c < 8; c++) {
      float sq = xn[r] + yn[c] - 2.f * acc[r][c];
      sq = fmaxf(sq, 1e-12f);
      float kv = __expf(-sqrtf(sq) * INV_EPS);
      __hip_bfloat16 h = __float2bfloat16(kv);
      outp[c] = *reinterpret_cast<u16*>(&h);
    }
    *(uint4*)(K + (size_t)(i0 + tr + r) * NN + j0 + tc) = *(uint4*)outp;
  }
}

// ---------------------------------------------------------------------------
// Kernel 3: initial column partials (u0 = 1/n), P bf16.
__global__ __launch_bounds__(256) void col0_k(const u16* __restrict__ K,
                                              u16* __restrict__ P) {
  int t = threadIdx.x;
  int b = blockIdx.x;
  int i0 = b * 16;
  float acc[4][8];
#pragma unroll
  for (int c = 0; c < 4; c++)
#pragma unroll
    for (int e = 0; e < 8; e++) acc[c][e] = 0.f;

  for (int r = 0; r < 16; r++) {
#pragma unroll
    for (int c = 0; c < 4; c++) {
      uint4 q = *(const uint4*)(K + (size_t)(i0 + r) * NN + c * 2048 + t * 8);
      float f[8];
      unpack8(q, f);
#pragma unroll
      for (int e = 0; e < 8; e++) acc[c][e] += f[e];
    }
  }
#pragma unroll
  for (int c = 0; c < 4; c++) {
    uint4 w;
    w.x = pkbf2(acc[c][0] * MARG, acc[c][1] * MARG);
    w.y = pkbf2(acc[c][2] * MARG, acc[c][3] * MARG);
    w.z = pkbf2(acc[c][4] * MARG, acc[c][5] * MARG);
    w.w = pkbf2(acc[c][6] * MARG, acc[c][7] * MARG);
    *(uint4*)(P + (size_t)b * NN + c * 2048 + t * 8) = w;
  }
}

// ---------------------------------------------------------------------------
// Kernel 4: reduce bf16 partials -> v[j] = b_j / sum_k P[k][j].
__global__ __launch_bounds__(256) void red_k(const u16* __restrict__ P,
                                             float* __restrict__ v) {
  int t = threadIdx.x;
  int j0 = blockIdx.x * 32;
  int jjp = t & 15;               // col-pair 0..15
  int kk  = t >> 4;               // 0..15, 32 partial rows each
  float s0 = 0.f, s1 = 0.f;
#pragma unroll 8
  for (int k = kk * 32; k < kk * 32 + 32; k++) {
    u32 w = *(const u32*)(P + (size_t)k * NN + j0 + jjp * 2);
    s0 += __uint_as_float(w << 16);
    s1 += __uint_as_float(w & 0xffff0000u);
  }
  __shared__ float red[256][2];
  red[t][0] = s0;
  red[t][1] = s1;
  __syncthreads();
  if (t < 16) {
    float t0 = 0.f, t1 = 0.f;
#pragma unroll
    for (int k = 0; k < 16; k++) {
      t0 += red[k * 16 + t][0];
      t1 += red[k * 16 + t][1];
    }
    v[j0 + t * 2]     = MARG / t0;
    v[j0 + t * 2 + 1] = MARG / t1;
  }
}

// ---------------------------------------------------------------------------
// Kernel 5 (hot loop): fused row-dot + column-partial.
// Block = 16 rows, 8 groups of 2 rows. Per group ONE barrier: wave-level
// __shfl_xor reduce -> per-wave partial in double-buffered wsum -> barrier ->
// every thread redundantly sums 4 wave partials and computes u.
// No prefetch pipeline (R2's spill lesson): q0/q1 (32 VGPR) only; latency
// hiding comes from 2 blocks/CU occupancy.
__global__ __launch_bounds__(256) void fused_k(const u16* __restrict__ K,
                                               const float* __restrict__ vin,
                                               float* __restrict__ uout,
                                               u16* __restrict__ P) {
  int t = threadIdx.x;
  int b = blockIdx.x;
  int i0 = b * 16;
  int wave = t >> 6;

  // v values for this thread's 32 columns
  float vv[4][8];
#pragma unroll
  for (int c = 0; c < 4; c++) {
    const float* vp = vin + c * 2048 + t * 8;
    float4 a = *(const float4*)vp;
    float4 bq = *(const float4*)(vp + 4);
    vv[c][0] = a.x;  vv[c][1] = a.y;  vv[c][2] = a.z;  vv[c][3] = a.w;
    vv[c][4] = bq.x; vv[c][5] = bq.y; vv[c][6] = bq.z; vv[c][7] = bq.w;
  }

  float acc[4][8];
#pragma unroll
  for (int c = 0; c < 4; c++)
#pragma unroll
    for (int e = 0; e < 8; e++) acc[c][e] = 0.f;

  __shared__ float wsum[2][4][2];   // [buf][wave][row]

  for (int rg = 0; rg < 8; rg++) {
    int i = i0 + rg * 2;
    uint4 q0[4], q1[4];
#pragma unroll
    for (int c = 0; c < 4; c++) {
      q0[c] = *(const uint4*)(K + (size_t)i * NN + c * 2048 + t * 8);
      q1[c] = *(const uint4*)(K + (size_t)(i + 1) * NN + c * 2048 + t * 8);
    }
    float s0 = 0.f, s1 = 0.f;
#pragma unroll
    for (int c = 0; c < 4; c++) {
      float f[8];
      unpack8(q0[c], f);
#pragma unroll
      for (int e = 0; e < 8; e++) s0 += f[e] * vv[c][e];
      unpack8(q1[c], f);
#pragma unroll
      for (int e = 0; e < 8; e++) s1 += f[e] * vv[c][e];
    }
    // wave-level reduce (64 lanes)
#pragma unroll
    for (int o = 32; o > 0; o >>= 1) {
      s0 += __shfl_xor(s0, o);
      s1 += __shfl_xor(s1, o);
    }
    if ((t & 63) == 0) {
      wsum[rg & 1][wave][0] = s0;
      wsum[rg & 1][wave][1] = s1;
    }
    __syncthreads();
    float u0 = MARG / (wsum[rg & 1][0][0] + wsum[rg & 1][1][0]
                     + wsum[rg & 1][2][0] + wsum[rg & 1][3][0]);
    float u1 = MARG / (wsum[rg & 1][0][1] + wsum[rg & 1][1][1]
                     + wsum[rg & 1][2][1] + wsum[rg & 1][3][1]);
    if (t < 2) uout[i + t] = (t == 0) ? u0 : u1;

    // accumulate column partials (re-unpack from regs)
#pragma unroll
    for (int c = 0; c < 4; c++) {
      float f[8];
      unpack8(q0[c], f);
#pragma unroll
      for (int e = 0; e < 8; e++) acc[c][e] += f[e] * u0;
      unpack8(q1[c], f);
#pragma unroll
      for (int e = 0; e < 8; e++) acc[c][e] += f[e] * u1;
    }
  }

#pragma unroll
  for (int c = 0; c < 4; c++) {
    uint4 w;
    w.x = pkbf2(acc[c][0], acc[c][1]);
    w.y = pkbf2(acc[c][2], acc[c][3]);
    w.z = pkbf2(acc[c][4], acc[c][5]);
    w.w = pkbf2(acc[c][6], acc[c][7]);
    *(uint4*)(P + (size_t)b * NN + c * 2048 + t * 8) = w;
  }
}

// ---------------------------------------------------------------------------
// Kernel 6: pi[i][j] = u_i * K[i][j] * v_j. 2048 blocks x 4 rows.
__global__ __launch_bounds__(256) void pi_k(const u16* __restrict__ K,
                                            const float* __restrict__ u,
                                            const float* __restrict__ v,
                                            float* __restrict__ out) {
  int t = threadIdx.x;
  int b = blockIdx.x;
  int i0 = b * 4;

  float vv[4][8];
#pragma unroll
  for (int c = 0; c < 4; c++) {
    const float* vp = v + c * 2048 + t * 8;
    float4 a = *(const float4*)vp;
    float4 bq = *(const float4*)(vp + 4);
    vv[c][0] = a.x;  vv[c][1] = a.y;  vv[c][2] = a.z;  vv[c][3] = a.w;
    vv[c][4] = bq.x; vv[c][5] = bq.y; vv[c][6] = bq.z; vv[c][7] = bq.w;
  }

#pragma unroll
  for (int r = 0; r < 4; r++) {
    int i = i0 + r;
    float uv = u[i];
#pragma unroll
    for (int c = 0; c < 4; c++) {
      uint4 q = *(const uint4*)(K + (size_t)i * NN + c * 2048 + t * 8);
      float f[8];
      unpack8(q, f);
      float4 lo = {uv * f[0] * vv[c][0], uv * f[1] * vv[c][1],
                   uv * f[2] * vv[c][2], uv * f[3] * vv[c][3]};
      float4 hi = {uv * f[4] * vv[c][4], uv * f[5] * vv[c][5],
                   uv * f[6] * vv[c][6], uv * f[7] * vv[c][7]};
      float* dst = out + (size_t)i * NN + c * 2048 + t * 8;
      *(float4*)dst = lo;
      *(float4*)(dst + 4) = hi;
    }
  }
}

// ---------------------------------------------------------------------------
extern "C" void kernel_launch(void* const* d_in, const int* in_sizes, int n_in,
                              void* d_out, int out_size, void* d_ws, size_t ws_size,
                              hipStream_t stream) {
  const float* x = (const float*)d_in[0];
  const float* y = (const float*)d_in[1];
  float* out = (float*)d_out;

  char* ws = (char*)d_ws;
  u16*  K  = (u16*)ws;                                     // 128 MiB
  u16*  P  = (u16*)(ws + (size_t)NN * NN * 2);             // 8 MiB (512 x 8192 bf16)
  float* xx = (float*)(ws + (size_t)NN * NN * 2 + (size_t)512 * NN * 2);
  float* yy = xx + NN;
  float* u  = yy + NN;
  float* v  = u + NN;

  norms_k<<<(2 * NN) / 256, 256, 0, stream>>>(x, y, xx, yy);
  build_k<<<128 * 64, 256, 0, stream>>>(x, y, xx, yy, K);
  col0_k<<<NN / 16, 256, 0, stream>>>(K, P);               // P = partials of K^T u0

  for (int it = 0; it < NITER; it++) {
    red_k<<<NN / 32, 256, 0, stream>>>(P, v);              // v = b / (K^T u)
    fused_k<<<NN / 16, 256, 0, stream>>>(K, v, u, P);      // u = a/(Kv); P = partials K^T u
  }
  red_k<<<NN / 32, 256, 0, stream>>>(P, v);                // final v
  pi_k<<<NN / 4, 256, 0, stream>>>(K, u, v, out);          // pi = u * K * v
}